// Round 1
// baseline (1389.343 us; speedup 1.0000x reference)
//
#include <hip/hip_runtime.h>
#include <hip/hip_bf16.h>

#define NTOK 8192
#define CDIM 1024
#define DIN  2048
#define NEXP 8
#define BK   64
#define LDA  72   // padded bf16 row stride for LDS tiles

typedef __bf16 bf16x8 __attribute__((ext_vector_type(8)));
typedef float  f32x4  __attribute__((ext_vector_type(4)));

__device__ __forceinline__ ushort f2bf(float f) {
    union { float f; unsigned u; } v; v.f = f;
    unsigned u = v.u;
    u += 0x7fffu + ((u >> 16) & 1u);   // round to nearest even
    return (ushort)(u >> 16);
}
__device__ __forceinline__ float silu_f(float x) { return x / (1.f + __expf(-x)); }

// ---------------- router: one wave per token ----------------
__global__ void __launch_bounds__(256) k_router(
    const float* __restrict__ x, const float* __restrict__ Wr,
    const float* __restrict__ br, int* __restrict__ counts,
    int* __restrict__ tok_e, float* __restrict__ tok_w) {
    int wave = blockIdx.x * 4 + (threadIdx.x >> 6);
    int lane = threadIdx.x & 63;
    const float4* row = (const float4*)(x + (size_t)wave * CDIM);
    float acc[NEXP];
#pragma unroll
    for (int e = 0; e < NEXP; ++e) acc[e] = 0.f;
#pragma unroll
    for (int j = 0; j < 4; ++j) {
        float4 v = row[j * 64 + lane];
#pragma unroll
        for (int e = 0; e < NEXP; ++e) {
            float4 w = ((const float4*)(Wr + e * CDIM))[j * 64 + lane];
            acc[e] += v.x * w.x + v.y * w.y + v.z * w.z + v.w * w.w;
        }
    }
#pragma unroll
    for (int off = 32; off > 0; off >>= 1)
#pragma unroll
        for (int e = 0; e < NEXP; ++e) acc[e] += __shfl_xor(acc[e], off, 64);
    if (lane == 0) {
        float l[NEXP];
#pragma unroll
        for (int e = 0; e < NEXP; ++e) l[e] = acc[e] + br[e];
        int i0 = 0; float l0 = l[0];
#pragma unroll
        for (int e = 1; e < NEXP; ++e) if (l[e] > l0) { l0 = l[e]; i0 = e; }
        int i1 = -1; float l1 = -1e30f;
#pragma unroll
        for (int e = 0; e < NEXP; ++e) if (e != i0 && l[e] > l1) { l1 = l[e]; i1 = e; }
        float s  = __expf(l1 - l0);        // softmax over top-2 == renormalized top-k probs
        float w0 = 1.f / (1.f + s);
        float w1 = 1.f - w0;
        tok_e[wave * 2] = i0; tok_e[wave * 2 + 1] = i1;
        tok_w[wave * 2] = w0; tok_w[wave * 2 + 1] = w1;
        atomicAdd(&counts[i0], 1); atomicAdd(&counts[i1], 1);
    }
}

// ---------------- scan + aux loss ----------------
__global__ void k_scan(const int* __restrict__ counts, int* __restrict__ offsets,
                       float* __restrict__ out_aux) {
    if (threadIdx.x == 0 && blockIdx.x == 0) {
        int o = 0;
        for (int e = 0; e < NEXP; ++e) { offsets[e] = o; o += counts[e]; }
        offsets[NEXP] = o;
        float aux = 0.f;
        for (int e = 0; e < NEXP; ++e) {
            float ld = (float)counts[e] * (1.f / (float)NTOK);
            aux += ld * ld;
        }
        *out_aux = aux;
    }
}

// ---------------- scatter tokens into expert-grouped slots ----------------
__global__ void __launch_bounds__(256) k_scatter(
    const int* __restrict__ tok_e, const float* __restrict__ tok_w,
    const int* __restrict__ offsets, int* __restrict__ cursor,
    int* __restrict__ perm_token, float* __restrict__ perm_w) {
    int t = blockIdx.x * 256 + threadIdx.x;
    if (t >= NTOK) return;
#pragma unroll
    for (int k = 0; k < 2; ++k) {
        int e = tok_e[t * 2 + k];
        int pos = atomicAdd(&cursor[e], 1);
        int s = offsets[e] + pos;
        perm_token[s] = t;
        perm_w[s] = tok_w[t * 2 + k];
    }
}

// ---------------- grouped GEMM1 + gated activation ----------------
// per tile: 64 slots x 64 y-cols; computes both xi (Win rows n) and z (Win rows DIN+n)
__global__ void __launch_bounds__(256) k_gemm1(
    const float* __restrict__ x, const float* __restrict__ Win,
    const float* __restrict__ conv_w, const float* __restrict__ conv_b,
    const float* __restrict__ Dp, const int* __restrict__ counts,
    const int* __restrict__ offsets, const int* __restrict__ perm_token,
    ushort* __restrict__ y) {
    const int NT = DIN / 64;   // 32
    const int SPLITM = 4;
    int bx = blockIdx.x;
    int e  = bx / (NT * SPLITM);
    int r  = bx % (NT * SPLITM);
    int nt = r / SPLITM, sp = r % SPLITM;
    int cnt = counts[e];
    if (cnt == 0) return;
    int base = offsets[e];
    int mtiles = (cnt + 63) >> 6;
    int n0 = nt * 64;

    __shared__ ushort a_lds[64 * LDA];
    __shared__ ushort b_lds[128 * LDA];
    __shared__ int    s_tok[64];

    int tid = threadIdx.x;
    int lane = tid & 63;
    int wid = tid >> 6;
    int wrow = wid >> 1, wcol = wid & 1;
    const float* WinE = Win + (size_t)e * (2 * DIN) * CDIM;

    for (int mt = sp; mt < mtiles; mt += SPLITM) {
        int rem = cnt - mt * 64;
        if (tid < 64) {
            int sidx = base + mt * 64 + tid;
            if (tid >= rem) sidx = base;   // clamp: any valid slot
            s_tok[tid] = perm_token[sidx];
        }
        __syncthreads();

        f32x4 accXi[2][2], accZ[2][2];
#pragma unroll
        for (int m = 0; m < 2; ++m)
#pragma unroll
            for (int n = 0; n < 2; ++n) {
                accXi[m][n] = f32x4{0.f, 0.f, 0.f, 0.f};
                accZ[m][n]  = f32x4{0.f, 0.f, 0.f, 0.f};
            }

        for (int kk0 = 0; kk0 < CDIM; kk0 += BK) {
            // stage A: 64 rows x 64 fp32 -> bf16 (coalesced: 16 threads/row)
#pragma unroll
            for (int j = 0; j < 4; ++j) {
                int g = tid + j * 256;
                int row = g >> 4;
                int col = (g & 15) * 4;
                float4 v = *(const float4*)(x + (size_t)s_tok[row] * CDIM + kk0 + col);
                ushort* dst = &a_lds[row * LDA + col];
                dst[0] = f2bf(v.x); dst[1] = f2bf(v.y); dst[2] = f2bf(v.z); dst[3] = f2bf(v.w);
            }
            // stage B: 128 rows (xi: n0+r / z: DIN+n0+r) x 64 fp32 -> bf16
#pragma unroll
            for (int j = 0; j < 8; ++j) {
                int g = tid + j * 256;
                int row = g >> 4;
                int col = (g & 15) * 4;
                int hrow = (row < 64) ? (n0 + row) : (DIN + n0 + (row - 64));
                float4 v = *(const float4*)(WinE + (size_t)hrow * CDIM + kk0 + col);
                ushort* dst = &b_lds[row * LDA + col];
                dst[0] = f2bf(v.x); dst[1] = f2bf(v.y); dst[2] = f2bf(v.z); dst[3] = f2bf(v.w);
            }
            __syncthreads();
#pragma unroll
            for (int kk = 0; kk < BK; kk += 32) {
                int kof = kk + (lane >> 4) * 8;
                bf16x8 af[2], bxi[2], bz[2];
#pragma unroll
                for (int m = 0; m < 2; ++m)
                    af[m] = *(const bf16x8*)&a_lds[(wrow * 32 + m * 16 + (lane & 15)) * LDA + kof];
#pragma unroll
                for (int n = 0; n < 2; ++n) {
                    int cl = wcol * 32 + n * 16 + (lane & 15);
                    bxi[n] = *(const bf16x8*)&b_lds[cl * LDA + kof];
                    bz[n]  = *(const bf16x8*)&b_lds[(64 + cl) * LDA + kof];
                }
#pragma unroll
                for (int m = 0; m < 2; ++m)
#pragma unroll
                    for (int n = 0; n < 2; ++n) {
                        accXi[m][n] = __builtin_amdgcn_mfma_f32_16x16x32_bf16(af[m], bxi[n], accXi[m][n], 0, 0, 0);
                        accZ[m][n]  = __builtin_amdgcn_mfma_f32_16x16x32_bf16(af[m], bz[n],  accZ[m][n],  0, 0, 0);
                    }
            }
            __syncthreads();
        }
        // epilogue: gated activation, store y (bf16)
#pragma unroll
        for (int n = 0; n < 2; ++n) {
            int c = n0 + wcol * 32 + n * 16 + (lane & 15);
            float cwl = conv_w[((size_t)e * DIN + c) * 4 + 3];
            float cb  = conv_b[(size_t)e * DIN + c];
            float dp  = Dp[(size_t)e * DIN + c];
#pragma unroll
            for (int m = 0; m < 2; ++m)
#pragma unroll
                for (int q = 0; q < 4; ++q) {
                    int rl = wrow * 32 + m * 16 + (lane >> 4) * 4 + q;
                    if (rl < rem) {
                        int slot = base + mt * 64 + rl;
                        float xi = accXi[m][n][q];
                        float z  = accZ[m][n][q];
                        float xa = silu_f(xi * cwl + cb);
                        float yv = xa * dp * silu_f(z);
                        y[(size_t)slot * DIN + c] = f2bf(yv);
                    }
                }
        }
        __syncthreads();
    }
}

// ---------------- grouped GEMM2 + weighted scatter-add ----------------
__global__ void __launch_bounds__(256) k_gemm2(
    const ushort* __restrict__ y, const float* __restrict__ Wout,
    const int* __restrict__ counts, const int* __restrict__ offsets,
    const int* __restrict__ perm_token, const float* __restrict__ perm_w,
    float* __restrict__ out) {
    const int NT = CDIM / 64;  // 16
    const int SPLITM = 4;
    int bx = blockIdx.x;
    int e  = bx / (NT * SPLITM);
    int r  = bx % (NT * SPLITM);
    int nt = r / SPLITM, sp = r % SPLITM;
    int cnt = counts[e];
    if (cnt == 0) return;
    int base = offsets[e];
    int mtiles = (cnt + 63) >> 6;
    int c0 = nt * 64;

    __shared__ ushort a_lds[64 * LDA];
    __shared__ ushort b_lds[64 * LDA];

    int tid = threadIdx.x, lane = tid & 63, wid = tid >> 6;
    int wrow = wid >> 1, wcol = wid & 1;
    const float* WoutE = Wout + (size_t)e * CDIM * DIN;

    for (int mt = sp; mt < mtiles; mt += SPLITM) {
        int rem = cnt - mt * 64;
        f32x4 acc[2][2];
#pragma unroll
        for (int m = 0; m < 2; ++m)
#pragma unroll
            for (int n = 0; n < 2; ++n) acc[m][n] = f32x4{0.f, 0.f, 0.f, 0.f};

        for (int kk0 = 0; kk0 < DIN; kk0 += BK) {
            // stage A: y rows (bf16 already), 64 rows x 64
#pragma unroll
            for (int j = 0; j < 2; ++j) {
                int g = tid + j * 256;
                int row = g >> 3;
                int col = (g & 7) * 8;
                int slot = base + mt * 64 + row;
                if (slot >= 2 * NTOK) slot = 2 * NTOK - 1;  // stay in-bounds; garbage rows discarded
                uint4 v = *(const uint4*)(y + (size_t)slot * DIN + kk0 + col);
                *(uint4*)&a_lds[row * LDA + col] = v;
            }
            // stage B: Wout rows (out cols), 64 rows x 64 fp32 -> bf16
#pragma unroll
            for (int j = 0; j < 4; ++j) {
                int g = tid + j * 256;
                int row = g >> 4;
                int col = (g & 15) * 4;
                float4 v = *(const float4*)(WoutE + (size_t)(c0 + row) * DIN + kk0 + col);
                ushort* dst = &b_lds[row * LDA + col];
                dst[0] = f2bf(v.x); dst[1] = f2bf(v.y); dst[2] = f2bf(v.z); dst[3] = f2bf(v.w);
            }
            __syncthreads();
#pragma unroll
            for (int kk = 0; kk < BK; kk += 32) {
                int kof = kk + (lane >> 4) * 8;
                bf16x8 af[2], bf[2];
#pragma unroll
                for (int m = 0; m < 2; ++m)
                    af[m] = *(const bf16x8*)&a_lds[(wrow * 32 + m * 16 + (lane & 15)) * LDA + kof];
#pragma unroll
                for (int n = 0; n < 2; ++n)
                    bf[n] = *(const bf16x8*)&b_lds[(wcol * 32 + n * 16 + (lane & 15)) * LDA + kof];
#pragma unroll
                for (int m = 0; m < 2; ++m)
#pragma unroll
                    for (int n = 0; n < 2; ++n)
                        acc[m][n] = __builtin_amdgcn_mfma_f32_16x16x32_bf16(af[m], bf[n], acc[m][n], 0, 0, 0);
            }
            __syncthreads();
        }
        // epilogue: scale by combine weight, atomic scatter-add into out
#pragma unroll
        for (int m = 0; m < 2; ++m)
#pragma unroll
            for (int q = 0; q < 4; ++q) {
                int rl = wrow * 32 + m * 16 + (lane >> 4) * 4 + q;
                if (rl < rem) {
                    int slot = base + mt * 64 + rl;
                    int t = perm_token[slot];
                    float w = perm_w[slot];
#pragma unroll
                    for (int n = 0; n < 2; ++n) {
                        int col = c0 + wcol * 32 + n * 16 + (lane & 15);
                        atomicAdd(&out[(size_t)t * CDIM + col], w * acc[m][n][q]);
                    }
                }
            }
        __syncthreads();
    }
}

extern "C" void kernel_launch(void* const* d_in, const int* in_sizes, int n_in,
                              void* d_out, int out_size, void* d_ws, size_t ws_size,
                              hipStream_t stream) {
    const float* x      = (const float*)d_in[0];
    const float* Wr     = (const float*)d_in[1];
    const float* br     = (const float*)d_in[2];
    const float* Win    = (const float*)d_in[3];
    const float* conv_w = (const float*)d_in[4];
    const float* conv_b = (const float*)d_in[5];
    const float* Dp     = (const float*)d_in[6];
    const float* Wout   = (const float*)d_in[7];
    float* out = (float*)d_out;

    char* ws = (char*)d_ws;
    int*    counts     = (int*)(ws + 0);
    int*    offsets    = (int*)(ws + 64);
    int*    cursor     = (int*)(ws + 128);
    int*    tok_e      = (int*)(ws + 256);
    float*  tok_w      = (float*)(ws + 256 + 65536);
    int*    perm_token = (int*)(ws + 256 + 2 * 65536);
    float*  perm_w     = (float*)(ws + 256 + 3 * 65536);
    ushort* y          = (ushort*)(ws + 256 + 4 * 65536 + 256);  // 16B aligned

    // zero control block + output accumulator
    hipMemsetAsync(ws, 0, 256, stream);
    hipMemsetAsync(d_out, 0, (size_t)out_size * sizeof(float), stream);

    k_router<<<NTOK / 4, 256, 0, stream>>>(x, Wr, br, counts, tok_e, tok_w);
    k_scan<<<1, 64, 0, stream>>>(counts, offsets, out + (size_t)NTOK * CDIM);
    k_scatter<<<NTOK / 256, 256, 0, stream>>>(tok_e, tok_w, offsets, cursor, perm_token, perm_w);
    k_gemm1<<<NEXP * (DIN / 64) * 4, 256, 0, stream>>>(x, Win, conv_w, conv_b, Dp,
                                                       counts, offsets, perm_token, y);
    k_gemm2<<<NEXP * (CDIM / 64) * 4, 256, 0, stream>>>(y, Wout, counts, offsets,
                                                        perm_token, perm_w, out);
}

// Round 2
// 865.751 us; speedup vs baseline: 1.6048x; 1.6048x over previous
//
#include <hip/hip_runtime.h>
#include <hip/hip_bf16.h>
#include <stdint.h>

#define NTOK 8192
#define CDIM 1024
#define DIN  2048
#define NEXP 8
#define NSLOT (NTOK * 2)

typedef __bf16 bf16x8 __attribute__((ext_vector_type(8)));
typedef float  f32x4  __attribute__((ext_vector_type(4)));

typedef __attribute__((address_space(1))) const unsigned char GBUF;
typedef __attribute__((address_space(3))) unsigned char LBUF;

__device__ __forceinline__ void gload_lds16(const void* g, void* l) {
    __builtin_amdgcn_global_load_lds((GBUF*)g, (LBUF*)l, 16, 0, 0);
}

__device__ __forceinline__ ushort f2bf(float f) {
    union { float f; unsigned u; } v; v.f = f;
    unsigned u = v.u;
    u += 0x7fffu + ((u >> 16) & 1u);   // RNE
    return (ushort)(u >> 16);
}
__device__ __forceinline__ float silu_f(float x) { return x / (1.f + __expf(-x)); }

// ---------------- fp32 -> bf16 bulk convert ----------------
__global__ void __launch_bounds__(256) k_cvt(const float* __restrict__ src,
                                             ushort* __restrict__ dst, int n4) {
    int i = blockIdx.x * 256 + threadIdx.x;
    int stride = gridDim.x * 256;
    for (; i < n4; i += stride) {
        float4 v = ((const float4*)src)[i];
        ushort4 o;
        o.x = f2bf(v.x); o.y = f2bf(v.y); o.z = f2bf(v.z); o.w = f2bf(v.w);
        ((ushort4*)dst)[i] = o;
    }
}

// ---------------- router: one wave per token ----------------
__global__ void __launch_bounds__(256) k_router(
    const float* __restrict__ x, const float* __restrict__ Wr,
    const float* __restrict__ br, int* __restrict__ counts,
    int* __restrict__ tok_e, float* __restrict__ tok_w) {
    int wave = blockIdx.x * 4 + (threadIdx.x >> 6);
    int lane = threadIdx.x & 63;
    const float4* row = (const float4*)(x + (size_t)wave * CDIM);
    float acc[NEXP];
#pragma unroll
    for (int e = 0; e < NEXP; ++e) acc[e] = 0.f;
#pragma unroll
    for (int j = 0; j < 4; ++j) {
        float4 v = row[j * 64 + lane];
#pragma unroll
        for (int e = 0; e < NEXP; ++e) {
            float4 w = ((const float4*)(Wr + e * CDIM))[j * 64 + lane];
            acc[e] += v.x * w.x + v.y * w.y + v.z * w.z + v.w * w.w;
        }
    }
#pragma unroll
    for (int off = 32; off > 0; off >>= 1)
#pragma unroll
        for (int e = 0; e < NEXP; ++e) acc[e] += __shfl_xor(acc[e], off, 64);
    if (lane == 0) {
        float l[NEXP];
#pragma unroll
        for (int e = 0; e < NEXP; ++e) l[e] = acc[e] + br[e];
        int i0 = 0; float l0 = l[0];
#pragma unroll
        for (int e = 1; e < NEXP; ++e) if (l[e] > l0) { l0 = l[e]; i0 = e; }
        int i1 = -1; float l1 = -1e30f;
#pragma unroll
        for (int e = 0; e < NEXP; ++e) if (e != i0 && l[e] > l1) { l1 = l[e]; i1 = e; }
        float s  = __expf(l1 - l0);   // renormalized top-2 softmax
        float w0 = 1.f / (1.f + s);
        float w1 = 1.f - w0;
        tok_e[wave * 2] = i0; tok_e[wave * 2 + 1] = i1;
        tok_w[wave * 2] = w0; tok_w[wave * 2 + 1] = w1;
        atomicAdd(&counts[i0], 1); atomicAdd(&counts[i1], 1);
    }
}

// ---------------- scan + aux loss ----------------
__global__ void k_scan(const int* __restrict__ counts, int* __restrict__ offsets,
                       float* __restrict__ out_aux) {
    if (threadIdx.x == 0 && blockIdx.x == 0) {
        int o = 0;
        for (int e = 0; e < NEXP; ++e) { offsets[e] = o; o += counts[e]; }
        offsets[NEXP] = o;
        float aux = 0.f;
        for (int e = 0; e < NEXP; ++e) {
            float ld = (float)counts[e] * (1.f / (float)NTOK);
            aux += ld * ld;
        }
        *out_aux = aux;
    }
}

// ---------------- scatter tokens into expert-grouped slots ----------------
__global__ void __launch_bounds__(256) k_scatter(
    const int* __restrict__ tok_e, const float* __restrict__ tok_w,
    const int* __restrict__ offsets, int* __restrict__ cursor,
    int* __restrict__ perm_token, float* __restrict__ perm_w) {
    int t = blockIdx.x * 256 + threadIdx.x;
    if (t >= NTOK) return;
#pragma unroll
    for (int k = 0; k < 2; ++k) {
        int e = tok_e[t * 2 + k];
        int pos = atomicAdd(&cursor[e], 1);
        int s = offsets[e] + pos;
        perm_token[s] = t;
        perm_w[s] = tok_w[t * 2 + k];
    }
}

// ---------------- grouped GEMM1 (bf16, global_load_lds) + gated act ----------------
// tile: 128 slots x 64 y-cols (dual: xi rows n0..n0+63, z rows DIN+n0..); BK=64
// grid = NEXP * 32 * 8 = 2048, XCD-swizzled
__global__ void __launch_bounds__(256) k_gemm1(
    const ushort* __restrict__ xb, const ushort* __restrict__ Winb,
    const float* __restrict__ conv_w, const float* __restrict__ conv_b,
    const float* __restrict__ Dp, const int* __restrict__ counts,
    const int* __restrict__ offsets, const int* __restrict__ perm_token,
    ushort* __restrict__ y) {
    int h = blockIdx.x;
    int vb = (h & 7) * 256 + (h >> 3);   // bijective: 2048 = 8*256
    int e  = vb >> 8;
    int r  = vb & 255;
    int nt = r >> 3;      // 32 n-tiles over DIN
    int sp = r & 7;       // SPLITM = 8
    int cnt = counts[e];
    if (cnt == 0) return;
    int base = offsets[e];
    int mtiles = (cnt + 127) >> 7;
    int n0 = nt * 64;

    __shared__ ushort a_lds[128 * 64];
    __shared__ ushort b_lds[128 * 64];
    __shared__ int    s_tok[128];

    int tid = threadIdx.x, lane = tid & 63, w = tid >> 6;
    int wrow = w >> 1, wcol = w & 1;
    const ushort* WinE = Winb + (size_t)e * (2 * DIN) * CDIM;

    // B global source offsets (fixed per block): lane covers 8 rows/waveload
    size_t bsrc[4];
#pragma unroll
    for (int i = 0; i < 4; ++i) {
        int rrow = (w + 4 * i) * 8 + (lane >> 3);           // 0..127
        int grow = (rrow < 64) ? (n0 + rrow) : (DIN + n0 + rrow - 64);
        bsrc[i] = (size_t)grow * CDIM + (lane & 7) * 8;
    }

    for (int mt = sp; mt < mtiles; mt += 8) {
        int rem = cnt - mt * 128;
        if (tid < 128) {
            int sidx = base + mt * 128 + (tid < rem ? tid : 0);
            s_tok[tid] = perm_token[sidx];
        }
        __syncthreads();
        size_t asrc[4];
#pragma unroll
        for (int i = 0; i < 4; ++i) {
            int row = (w + 4 * i) * 8 + (lane >> 3);
            asrc[i] = (size_t)s_tok[row] * CDIM + (lane & 7) * 8;
        }
        f32x4 accXi[4][2], accZ[4][2];
#pragma unroll
        for (int m = 0; m < 4; ++m)
#pragma unroll
            for (int n = 0; n < 2; ++n) {
                accXi[m][n] = f32x4{0.f, 0.f, 0.f, 0.f};
                accZ[m][n]  = f32x4{0.f, 0.f, 0.f, 0.f};
            }

        for (int kk0 = 0; kk0 < CDIM; kk0 += 64) {
#pragma unroll
            for (int i = 0; i < 4; ++i) {
                gload_lds16(xb + asrc[i] + kk0,  &a_lds[(w + 4 * i) * 512]);
                gload_lds16(WinE + bsrc[i] + kk0, &b_lds[(w + 4 * i) * 512]);
            }
            __syncthreads();
#pragma unroll
            for (int kk = 0; kk < 64; kk += 32) {
                int kof = kk + (lane >> 4) * 8;
                bf16x8 af[4], bxi[2], bz[2];
#pragma unroll
                for (int m = 0; m < 4; ++m)
                    af[m] = *(const bf16x8*)&a_lds[(wrow * 64 + m * 16 + (lane & 15)) * 64 + kof];
#pragma unroll
                for (int n = 0; n < 2; ++n) {
                    int cl = wcol * 32 + n * 16 + (lane & 15);
                    bxi[n] = *(const bf16x8*)&b_lds[cl * 64 + kof];
                    bz[n]  = *(const bf16x8*)&b_lds[(64 + cl) * 64 + kof];
                }
#pragma unroll
                for (int m = 0; m < 4; ++m)
#pragma unroll
                    for (int n = 0; n < 2; ++n) {
                        accXi[m][n] = __builtin_amdgcn_mfma_f32_16x16x32_bf16(af[m], bxi[n], accXi[m][n], 0, 0, 0);
                        accZ[m][n]  = __builtin_amdgcn_mfma_f32_16x16x32_bf16(af[m], bz[n],  accZ[m][n],  0, 0, 0);
                    }
            }
            __syncthreads();
        }
#pragma unroll
        for (int n = 0; n < 2; ++n) {
            int c = n0 + wcol * 32 + n * 16 + (lane & 15);
            float cwl = conv_w[((size_t)e * DIN + c) * 4 + 3];
            float cb  = conv_b[(size_t)e * DIN + c];
            float dp  = Dp[(size_t)e * DIN + c];
#pragma unroll
            for (int m = 0; m < 4; ++m)
#pragma unroll
                for (int q = 0; q < 4; ++q) {
                    int rl = wrow * 64 + m * 16 + (lane >> 4) * 4 + q;
                    if (rl < rem) {
                        int slot = base + mt * 128 + rl;
                        float xi = accXi[m][n][q], z = accZ[m][n][q];
                        float yv = silu_f(xi * cwl + cb) * dp * silu_f(z);
                        y[(size_t)slot * DIN + c] = f2bf(yv);
                    }
                }
        }
        __syncthreads();
    }
}

// ---------------- grouped GEMM2 (bf16) + weighted scatter-add ----------------
// tile: 128 slots x 128 out-cols; grid = NEXP * 8 * 16 = 1024, XCD-swizzled
__global__ void __launch_bounds__(256) k_gemm2(
    const ushort* __restrict__ y, const ushort* __restrict__ Woutb,
    const int* __restrict__ counts, const int* __restrict__ offsets,
    const int* __restrict__ perm_token, const float* __restrict__ perm_w,
    float* __restrict__ out) {
    int h = blockIdx.x;
    int vb = (h & 7) * 128 + (h >> 3);   // bijective: 1024 = 8*128
    int e  = vb >> 7;
    int r  = vb & 127;
    int nt = r >> 4;      // 8 n-tiles over CDIM
    int sp = r & 15;      // SPLITM = 16
    int cnt = counts[e];
    if (cnt == 0) return;
    int base = offsets[e];
    int mtiles = (cnt + 127) >> 7;
    int c0 = nt * 128;

    __shared__ ushort a_lds[128 * 64];
    __shared__ ushort b_lds[128 * 64];

    int tid = threadIdx.x, lane = tid & 63, w = tid >> 6;
    int wrow = w >> 1, wcol = w & 1;
    const ushort* WoutE = Woutb + (size_t)e * CDIM * DIN;

    size_t bsrc[4];
#pragma unroll
    for (int i = 0; i < 4; ++i) {
        int rrow = (w + 4 * i) * 8 + (lane >> 3);
        bsrc[i] = (size_t)(c0 + rrow) * DIN + (lane & 7) * 8;
    }

    for (int mt = sp; mt < mtiles; mt += 16) {
        int rem = cnt - mt * 128;
        size_t asrc[4];
#pragma unroll
        for (int i = 0; i < 4; ++i) {
            int rr = (w + 4 * i) * 8 + (lane >> 3);
            int slot = base + mt * 128 + (rr < rem ? rr : 0);
            asrc[i] = (size_t)slot * DIN + (lane & 7) * 8;
        }
        f32x4 acc[4][4];
#pragma unroll
        for (int m = 0; m < 4; ++m)
#pragma unroll
            for (int n = 0; n < 4; ++n) acc[m][n] = f32x4{0.f, 0.f, 0.f, 0.f};

        for (int kk0 = 0; kk0 < DIN; kk0 += 64) {
#pragma unroll
            for (int i = 0; i < 4; ++i) {
                gload_lds16(y + asrc[i] + kk0,     &a_lds[(w + 4 * i) * 512]);
                gload_lds16(WoutE + bsrc[i] + kk0, &b_lds[(w + 4 * i) * 512]);
            }
            __syncthreads();
#pragma unroll
            for (int kk = 0; kk < 64; kk += 32) {
                int kof = kk + (lane >> 4) * 8;
                bf16x8 af[4], bfr[4];
#pragma unroll
                for (int m = 0; m < 4; ++m)
                    af[m] = *(const bf16x8*)&a_lds[(wrow * 64 + m * 16 + (lane & 15)) * 64 + kof];
#pragma unroll
                for (int n = 0; n < 4; ++n)
                    bfr[n] = *(const bf16x8*)&b_lds[(wcol * 64 + n * 16 + (lane & 15)) * 64 + kof];
#pragma unroll
                for (int m = 0; m < 4; ++m)
#pragma unroll
                    for (int n = 0; n < 4; ++n)
                        acc[m][n] = __builtin_amdgcn_mfma_f32_16x16x32_bf16(af[m], bfr[n], acc[m][n], 0, 0, 0);
            }
            __syncthreads();
        }
#pragma unroll
        for (int m = 0; m < 4; ++m)
#pragma unroll
            for (int q = 0; q < 4; ++q) {
                int rl = wrow * 64 + m * 16 + (lane >> 4) * 4 + q;
                if (rl < rem) {
                    int slot = base + mt * 128 + rl;
                    int t = perm_token[slot];
                    float wgt = perm_w[slot];
#pragma unroll
                    for (int n = 0; n < 4; ++n) {
                        int col = c0 + wcol * 64 + n * 16 + (lane & 15);
                        atomicAdd(&out[(size_t)t * CDIM + col], wgt * acc[m][n][q]);
                    }
                }
            }
    }
}

extern "C" void kernel_launch(void* const* d_in, const int* in_sizes, int n_in,
                              void* d_out, int out_size, void* d_ws, size_t ws_size,
                              hipStream_t stream) {
    const float* x      = (const float*)d_in[0];
    const float* Wr     = (const float*)d_in[1];
    const float* br     = (const float*)d_in[2];
    const float* Win    = (const float*)d_in[3];
    const float* conv_w = (const float*)d_in[4];
    const float* conv_b = (const float*)d_in[5];
    const float* Dp     = (const float*)d_in[6];
    const float* Wout   = (const float*)d_in[7];
    float* out = (float*)d_out;

    char* ws = (char*)d_ws;
    int*    counts     = (int*)(ws + 0);
    int*    offsets    = (int*)(ws + 64);
    int*    cursor     = (int*)(ws + 128);
    int*    tok_e      = (int*)(ws + 4096);
    float*  tok_w      = (float*)(ws + 4096 + 65536);
    int*    perm_token = (int*)(ws + 4096 + 2 * 65536);
    float*  perm_w     = (float*)(ws + 4096 + 3 * 65536);
    ushort* y          = (ushort*)(ws + 4096 + 4 * 65536);                    // 64 MB
    ushort* xb         = (ushort*)(ws + 4096 + 4 * 65536 + 67108864);         // 16 MB
    ushort* winb       = (ushort*)(ws + 4096 + 4 * 65536 + 67108864 + 16777216);   // 64 MB
    ushort* woutb      = (ushort*)(ws + 4096 + 4 * 65536 + 67108864 + 16777216 + 67108864); // 32 MB

    hipMemsetAsync(ws, 0, 256, stream);
    hipMemsetAsync(d_out, 0, (size_t)out_size * sizeof(float), stream);

    k_cvt<<<1024, 256, 0, stream>>>(x,    xb,    NTOK * CDIM / 4);
    k_cvt<<<2048, 256, 0, stream>>>(Win,  winb,  NEXP * 2 * DIN * CDIM / 4);
    k_cvt<<<1024, 256, 0, stream>>>(Wout, woutb, NEXP * CDIM * DIN / 4);

    k_router<<<NTOK / 4, 256, 0, stream>>>(x, Wr, br, counts, tok_e, tok_w);
    k_scan<<<1, 64, 0, stream>>>(counts, offsets, out + (size_t)NTOK * CDIM);
    k_scatter<<<NTOK / 256, 256, 0, stream>>>(tok_e, tok_w, offsets, cursor, perm_token, perm_w);

    k_gemm1<<<NEXP * 32 * 8, 256, 0, stream>>>(xb, winb, conv_w, conv_b, Dp,
                                               counts, offsets, perm_token, y);
    k_gemm2<<<NEXP * 8 * 16, 256, 0, stream>>>(y, woutb, counts, offsets,
                                               perm_token, perm_w, out);
}